// Round 7
// baseline (197.216 us; speedup 1.0000x reference)
//
#include <hip/hip_runtime.h>
#include <math.h>

// Problem constants
#define B_    8
#define C_    192
#define N_    3136          // H*W
#define K_    9
#define C2_   384
#define OUT_  192
#define M_    (B_ * N_)     // 25088 rows
#define EPS_  1e-5f

typedef __bf16 bf16;
typedef __bf16 bf16x2 __attribute__((ext_vector_type(2)));
typedef __bf16 bf16x8 __attribute__((ext_vector_type(8)));
typedef float  f32x4  __attribute__((ext_vector_type(4)));

__device__ __forceinline__ float gelu_f(float x) {
    return 0.5f * x * (1.0f + erff(x * 0.70710678118654752440f));
}

// async global->LDS, 16B per lane; lds base must be wave-uniform
__device__ __forceinline__ void gl_lds16(const void* g, void* l) {
    __builtin_amdgcn_global_load_lds(
        (const __attribute__((address_space(1))) unsigned int*)g,
        (__attribute__((address_space(3))) unsigned int*)l, 16, 0, 0);
}

// Swizzled LDS tile layout: tile is [rows][64] bf16, stored as 16B chunks.
// Logical chunk (r, c8) lives at slot r*8 + (c8 ^ (r&7)); element offset slot*8.
__device__ __forceinline__ int sw_off(int r, int c8) {
    return (r * 8 + (c8 ^ (r & 7))) * 8;
}

// ---------------------------------------------------------------------------
// k_pre: z<8 -> transpose x fp32 [B,C,N] -> xt bf16 [B,N,C]
//        z==8 -> cast+permute w1 -> w1p, cast w2 -> w2b, zero stats
// grid (49, 6, 9), block 256
__global__ __launch_bounds__(256) void k_pre(const float* __restrict__ x,
                                             bf16* __restrict__ xt,
                                             const float* __restrict__ w1,
                                             const float* __restrict__ w2,
                                             bf16* __restrict__ w1p,
                                             bf16* __restrict__ w2b,
                                             float* __restrict__ stats) {
    if (blockIdx.z == 8) {
        const int bid = blockIdx.y * 49 + blockIdx.x;        // 0..293
        #pragma unroll
        for (int t = 0; t < 2; ++t) {
            const int idx = bid * 512 + t * 256 + threadIdx.x;
            if (idx < C2_ * C2_) {
                const int o  = idx / C2_;
                const int cc = idx - o * C2_;
                const int src = (cc < C_) ? (2 * cc) : (2 * (cc - C_) + 1);
                w1p[idx] = (bf16)w1[o * C2_ + src];
            }
            if (idx < OUT_ * C2_) w2b[idx] = (bf16)w2[idx];
            if (idx < 1152) stats[idx] = 0.f;   // p1s[384] p1q[384] p2s[192] p2q[192]
        }
        return;
    }
    __shared__ float T[32][65];
    const int b  = blockIdx.z;
    const int c0 = blockIdx.y * 32;
    const int n0 = blockIdx.x * 64;
    const int tid = threadIdx.x;
    {
        const int nl = tid & 63;
        const int cl = tid >> 6;
        #pragma unroll
        for (int r = 0; r < 8; ++r) {
            const int c = cl + r * 4;
            T[c][nl] = x[((size_t)b * C_ + (c0 + c)) * N_ + n0 + nl];
        }
    }
    __syncthreads();
    {
        const int cl = tid & 31;
        const int nl = tid >> 5;
        #pragma unroll
        for (int r = 0; r < 8; ++r) {
            const int n = nl + r * 8;
            xt[((size_t)b * N_ + n0 + n) * C_ + c0 + cl] = (bf16)T[cl][n];
        }
    }
}

// ---------------------------------------------------------------------------
// Feats (diff half): d[node][c] = max_k( xt[j_k][c] - xt[i_k][c] )
// 2 nodes per block, bf16x2 per thread (channel pairs). grid M/2, block 192
__global__ __launch_bounds__(192) void k_feats(const bf16* __restrict__ xt,
                                               const int* __restrict__ eidx,
                                               bf16* __restrict__ dbuf) {
    const int t    = threadIdx.x;
    const int half = (t >= 96) ? 1 : 0;
    const int cp   = t - half * 96;                  // 0..95 -> channels 2cp,2cp+1
    const int node = blockIdx.x * 2 + half;
    const int b    = node / N_;
    const int* e0 = eidx + (size_t)node * K_;
    const int* e1 = e0 + (size_t)M_ * K_;
    const bf16* xb = xt + (size_t)b * N_ * C_;
    float mx0 = -1e30f, mx1 = -1e30f;
    #pragma unroll
    for (int k = 0; k < K_; ++k) {
        const int j = e0[k];
        const int i = e1[k];
        const bf16x2 aj = *(const bf16x2*)&xb[(size_t)j * C_ + 2 * cp];
        const bf16x2 ai = *(const bf16x2*)&xb[(size_t)i * C_ + 2 * cp];
        mx0 = fmaxf(mx0, (float)aj[0] - (float)ai[0]);
        mx1 = fmaxf(mx1, (float)aj[1] - (float)ai[1]);
    }
    bf16x2 o; o[0] = (bf16)mx0; o[1] = (bf16)mx1;
    *(bf16x2*)&dbuf[(size_t)node * C_ + 2 * cp] = o;
}

// ---------------------------------------------------------------------------
// GEMM1: h1[m,o] = sum_c [X|D][m,c] * w1p[o,c] + b1[o] -> bf16, fused stats
// 64x128 tile, BK=64, swizzled LDS, 4 waves x (2x4) 16x16x32 frags
// grid (392, 3), block 256  -> 1176 blocks, ~4.6/CU
__global__ __launch_bounds__(256) void k_gemm1(const bf16* __restrict__ X,
                                               const bf16* __restrict__ D,
                                               const bf16* __restrict__ Wp,
                                               const float* __restrict__ bias,
                                               bf16* __restrict__ H1,
                                               float* __restrict__ psum,
                                               float* __restrict__ psq) {
    __shared__ bf16 As[64 * 64];    // 8 KB
    __shared__ bf16 Bs[128 * 64];   // 16 KB
    const int tid  = threadIdx.x;
    const int lane = tid & 63;
    const int wv   = tid >> 6;
    const int l16  = lane & 15;
    const int quad = lane >> 4;
    const int m0   = blockIdx.x * 64;
    const int n0   = blockIdx.y * 128;
    const int wm   = (wv & 1) * 32;
    const int wn   = (wv >> 1) * 64;

    f32x4 acc[2][4] = {};

    for (int kk = 0; kk < C2_; kk += 64) {
        __syncthreads();
        const bf16* asrc = (kk < C_) ? X : D;
        const int   acol = (kk < C_) ? kk : (kk - C_);
        #pragma unroll
        for (int i = 0; i < 2; ++i) {              // A: 512 chunks
            const int qb = wv * 128 + i * 64;
            const int q  = qb + lane;
            const int r  = q >> 3;
            const int c8 = (q & 7) ^ (r & 7);
            gl_lds16(asrc + (size_t)(m0 + r) * C_ + acol + c8 * 8, &As[qb * 8]);
        }
        #pragma unroll
        for (int i = 0; i < 4; ++i) {              // B: 1024 chunks
            const int qb = wv * 256 + i * 64;
            const int q  = qb + lane;
            const int r  = q >> 3;
            const int c8 = (q & 7) ^ (r & 7);
            gl_lds16(Wp + (size_t)(n0 + r) * C2_ + kk + c8 * 8, &Bs[qb * 8]);
        }
        __syncthreads();
        #pragma unroll
        for (int ks = 0; ks < 2; ++ks) {
            bf16x8 af[2], bfr[4];
            #pragma unroll
            for (int f = 0; f < 2; ++f)
                af[f] = *(const bf16x8*)&As[sw_off(wm + f * 16 + l16, ks * 4 + quad)];
            #pragma unroll
            for (int f = 0; f < 4; ++f)
                bfr[f] = *(const bf16x8*)&Bs[sw_off(wn + f * 16 + l16, ks * 4 + quad)];
            #pragma unroll
            for (int mf = 0; mf < 2; ++mf)
                #pragma unroll
                for (int nf = 0; nf < 4; ++nf)
                    acc[mf][nf] = __builtin_amdgcn_mfma_f32_16x16x32_bf16(
                        af[mf], bfr[nf], acc[mf][nf], 0, 0, 0);
        }
    }

    #pragma unroll
    for (int nf = 0; nf < 4; ++nf) {
        const int col = n0 + wn + nf * 16 + l16;
        const float bv = bias[col];
        float s = 0.f, q = 0.f;
        #pragma unroll
        for (int mf = 0; mf < 2; ++mf) {
            #pragma unroll
            for (int r = 0; r < 4; ++r) {
                const float v = acc[mf][nf][r] + bv;
                s += v; q += v * v;
                H1[(size_t)(m0 + wm + mf * 16 + quad * 4 + r) * C2_ + col] = (bf16)v;
            }
        }
        s += __shfl_xor(s, 16); s += __shfl_xor(s, 32);
        q += __shfl_xor(q, 16); q += __shfl_xor(q, 32);
        if (quad == 0) { atomicAdd(&psum[col], s); atomicAdd(&psq[col], q); }
    }
}

// ---------------------------------------------------------------------------
// Activation: a1 = bf16(gelu(h1*sc + sh)). BN1 params once per block in LDS.
// grid 1176, block 256, 32 elems/thread
__global__ __launch_bounds__(256) void k_act(const bf16* __restrict__ H1,
                                             const float* __restrict__ p1s,
                                             const float* __restrict__ p1q,
                                             const float* __restrict__ g,
                                             const float* __restrict__ beta,
                                             bf16* __restrict__ A1) {
    __shared__ float s_sc[C2_], s_sh[C2_];
    for (int c = threadIdx.x; c < C2_; c += 256) {
        const float mean = p1s[c] * (1.0f / (float)M_);
        const float var  = p1q[c] * (1.0f / (float)M_) - mean * mean;
        const float inv  = rsqrtf(var + EPS_);
        const float scl  = g[c] * inv;
        s_sc[c] = scl;
        s_sh[c] = beta[c] - mean * scl;
    }
    __syncthreads();
    #pragma unroll
    for (int t = 0; t < 4; ++t) {
        const size_t chunk = (size_t)blockIdx.x * 1024 + t * 256 + threadIdx.x;
        const size_t i8 = chunk * 8;
        const int c0 = (int)(i8 % C2_);
        const bf16x8 v = *(const bf16x8*)&H1[i8];
        const float4 sca = *(const float4*)&s_sc[c0];
        const float4 scb = *(const float4*)&s_sc[c0 + 4];
        const float4 sha = *(const float4*)&s_sh[c0];
        const float4 shb = *(const float4*)&s_sh[c0 + 4];
        const float scs[8] = {sca.x, sca.y, sca.z, sca.w, scb.x, scb.y, scb.z, scb.w};
        const float shs[8] = {sha.x, sha.y, sha.z, sha.w, shb.x, shb.y, shb.z, shb.w};
        bf16x8 o;
        #pragma unroll
        for (int j = 0; j < 8; ++j)
            o[j] = (bf16)gelu_f(fmaf((float)v[j], scs[j], shs[j]));
        *(bf16x8*)&A1[i8] = o;
    }
}

// ---------------------------------------------------------------------------
// GEMM2: h2[m,o] = sum_c a1[m,c]*w2[o,c] + b2[o] -> bf16, fused stats
// 64x64 tile, BK=64, swizzled LDS, 4 waves x (2x2) frags
// grid (392, 3), block 256
__global__ __launch_bounds__(256) void k_gemm2(const bf16* __restrict__ A1,
                                               const bf16* __restrict__ W2,
                                               const float* __restrict__ bias,
                                               bf16* __restrict__ H2,
                                               float* __restrict__ psum,
                                               float* __restrict__ psq) {
    __shared__ bf16 As[64 * 64];    // 8 KB
    __shared__ bf16 Bs[64 * 64];    // 8 KB
    const int tid  = threadIdx.x;
    const int lane = tid & 63;
    const int wv   = tid >> 6;
    const int l16  = lane & 15;
    const int quad = lane >> 4;
    const int m0   = blockIdx.x * 64;
    const int n0   = blockIdx.y * 64;
    const int wm   = (wv & 1) * 32;
    const int wn   = (wv >> 1) * 32;

    f32x4 acc[2][2] = {};

    for (int kk = 0; kk < C2_; kk += 64) {
        __syncthreads();
        #pragma unroll
        for (int i = 0; i < 2; ++i) {              // A: 512 chunks
            const int qb = wv * 128 + i * 64;
            const int q  = qb + lane;
            const int r  = q >> 3;
            const int c8 = (q & 7) ^ (r & 7);
            gl_lds16(A1 + (size_t)(m0 + r) * C2_ + kk + c8 * 8, &As[qb * 8]);
        }
        #pragma unroll
        for (int i = 0; i < 2; ++i) {              // B: 512 chunks
            const int qb = wv * 128 + i * 64;
            const int q  = qb + lane;
            const int r  = q >> 3;
            const int c8 = (q & 7) ^ (r & 7);
            gl_lds16(W2 + (size_t)(n0 + r) * C2_ + kk + c8 * 8, &Bs[qb * 8]);
        }
        __syncthreads();
        #pragma unroll
        for (int ks = 0; ks < 2; ++ks) {
            bf16x8 af[2], bfr[2];
            #pragma unroll
            for (int f = 0; f < 2; ++f) {
                af[f]  = *(const bf16x8*)&As[sw_off(wm + f * 16 + l16, ks * 4 + quad)];
                bfr[f] = *(const bf16x8*)&Bs[sw_off(wn + f * 16 + l16, ks * 4 + quad)];
            }
            #pragma unroll
            for (int mf = 0; mf < 2; ++mf)
                #pragma unroll
                for (int nf = 0; nf < 2; ++nf)
                    acc[mf][nf] = __builtin_amdgcn_mfma_f32_16x16x32_bf16(
                        af[mf], bfr[nf], acc[mf][nf], 0, 0, 0);
        }
    }

    #pragma unroll
    for (int nf = 0; nf < 2; ++nf) {
        const int col = n0 + wn + nf * 16 + l16;
        const float bv = bias[col];
        float s = 0.f, q = 0.f;
        #pragma unroll
        for (int mf = 0; mf < 2; ++mf) {
            #pragma unroll
            for (int r = 0; r < 4; ++r) {
                const float v = acc[mf][nf][r] + bv;
                s += v; q += v * v;
                H2[(size_t)(m0 + wm + mf * 16 + quad * 4 + r) * OUT_ + col] = (bf16)v;
            }
        }
        s += __shfl_xor(s, 16); s += __shfl_xor(s, 32);
        q += __shfl_xor(q, 16); q += __shfl_xor(q, 32);
        if (quad == 0) { atomicAdd(&psum[col], s); atomicAdd(&psq[col], q); }
    }
}

// ---------------------------------------------------------------------------
// Output: BN2+GELU + transpose [M,OUT] bf16 -> [B,OUT,N] fp32
// grid (N/64, OUT/32, B), block 256
__global__ __launch_bounds__(256) void k_out(const bf16* __restrict__ H2,
                                             const float* __restrict__ p2s,
                                             const float* __restrict__ p2q,
                                             const float* __restrict__ g,
                                             const float* __restrict__ beta,
                                             float* __restrict__ out) {
    __shared__ float T[64][33];
    const int b  = blockIdx.z;
    const int o0 = blockIdx.y * 32;
    const int n0 = blockIdx.x * 64;
    const int tid = threadIdx.x;
    {
        const int ol = tid & 31;
        const int nl = tid >> 5;
        const int o  = o0 + ol;
        const float mean  = p2s[o] * (1.0f / (float)M_);
        const float var   = p2q[o] * (1.0f / (float)M_) - mean * mean;
        const float inv   = rsqrtf(var + EPS_);
        const float scale = g[o] * inv;
        const float shift = beta[o] - mean * scale;
        #pragma unroll
        for (int r = 0; r < 8; ++r) {
            const int n = nl + r * 8;
            const float v = (float)H2[((size_t)b * N_ + n0 + n) * OUT_ + o];
            T[n][ol] = gelu_f(fmaf(v, scale, shift));
        }
    }
    __syncthreads();
    {
        const int nl = tid & 63;
        const int ol = tid >> 6;
        #pragma unroll
        for (int r = 0; r < 8; ++r) {
            const int o = ol + r * 4;
            out[((size_t)b * OUT_ + o0 + o) * N_ + n0 + nl] = T[nl][o];
        }
    }
}

// ---------------------------------------------------------------------------
extern "C" void kernel_launch(void* const* d_in, const int* in_sizes, int n_in,
                              void* d_out, int out_size, void* d_ws, size_t ws_size,
                              hipStream_t stream) {
    const float* x     = (const float*)d_in[0];
    const int*   eidx  = (const int*)  d_in[1];
    const float* w1    = (const float*)d_in[2];
    const float* b1    = (const float*)d_in[3];
    const float* g1    = (const float*)d_in[4];
    const float* beta1 = (const float*)d_in[5];
    const float* w2    = (const float*)d_in[6];
    const float* b2    = (const float*)d_in[7];
    const float* g2    = (const float*)d_in[8];
    const float* beta2 = (const float*)d_in[9];
    float* out = (float*)d_out;

    char* ws = (char*)d_ws;
    size_t off = 0;
    bf16*  xt    = (bf16*)(ws + off); off += (size_t)M_ * C_  * sizeof(bf16);
    bf16*  dbuf  = (bf16*)(ws + off); off += (size_t)M_ * C_  * sizeof(bf16);
    bf16*  h1    = (bf16*)(ws + off); off += (size_t)M_ * C2_ * sizeof(bf16);
    bf16*  a1    = (bf16*)(ws + off); off += (size_t)M_ * C2_ * sizeof(bf16);
    bf16*  h2    = (bf16*)(ws + off); off += (size_t)M_ * OUT_ * sizeof(bf16);
    bf16*  w1p   = (bf16*)(ws + off); off += (size_t)C2_ * C2_ * sizeof(bf16);
    bf16*  w2b   = (bf16*)(ws + off); off += (size_t)OUT_ * C2_ * sizeof(bf16);
    float* stats = (float*)(ws + off); off += 1152 * sizeof(float);
    float* p1s = stats;        // 384
    float* p1q = stats + 384;  // 384
    float* p2s = stats + 768;  // 192
    float* p2q = stats + 960;  // 192

    k_pre<<<dim3(N_ / 64, C_ / 32, B_ + 1), 256, 0, stream>>>(x, xt, w1, w2, w1p, w2b, stats);
    k_feats<<<M_ / 2, 192, 0, stream>>>(xt, eidx, dbuf);
    k_gemm1<<<dim3(M_ / 64, C2_ / 128), 256, 0, stream>>>(xt, dbuf, w1p, b1, h1, p1s, p1q);
    k_act<<<1176, 256, 0, stream>>>(h1, p1s, p1q, g1, beta1, a1);
    k_gemm2<<<dim3(M_ / 64, OUT_ / 64), 256, 0, stream>>>(a1, w2b, b2, h2, p2s, p2q);
    k_out<<<dim3(N_ / 64, OUT_ / 32, B_), 256, 0, stream>>>(h2, p2s, p2q, g2, beta2, out);
}

// Round 8
// 175.536 us; speedup vs baseline: 1.1235x; 1.1235x over previous
//
#include <hip/hip_runtime.h>
#include <math.h>

// Problem constants
#define B_    8
#define C_    192
#define N_    3136          // H*W
#define K_    9
#define C2_   384
#define OUT_  192
#define M_    (B_ * N_)     // 25088 rows
#define EPS_  1e-5f

typedef __bf16 bf16;
typedef __bf16 bf16x2 __attribute__((ext_vector_type(2)));
typedef __bf16 bf16x8 __attribute__((ext_vector_type(8)));
typedef float  f32x4  __attribute__((ext_vector_type(4)));

__device__ __forceinline__ float gelu_f(float x) {
    return 0.5f * x * (1.0f + erff(x * 0.70710678118654752440f));
}

// async global->LDS, 16B per lane; lds base must be wave-uniform
__device__ __forceinline__ void gl_lds16(const void* g, void* l) {
    __builtin_amdgcn_global_load_lds(
        (const __attribute__((address_space(1))) unsigned int*)g,
        (__attribute__((address_space(3))) unsigned int*)l, 16, 0, 0);
}

// Swizzled LDS tile layout: tile is [rows][64] bf16, stored as 16B chunks.
// Logical chunk (r, c8) lives at slot r*8 + (c8 ^ (r&7)); element offset slot*8.
__device__ __forceinline__ int sw_off(int r, int c8) {
    return (r * 8 + (c8 ^ (r & 7))) * 8;
}

// ---------------------------------------------------------------------------
// k_pre: z<8 -> transpose x fp32 [B,C,N] -> xt bf16 [B,N,C]  (64x64 tiles)
//        z==8 -> cast+permute w1 -> w1p, cast w2 -> w2b, zero stats
// grid (49, 3, 9), block 256
__global__ __launch_bounds__(256) void k_pre(const float* __restrict__ x,
                                             bf16* __restrict__ xt,
                                             const float* __restrict__ w1,
                                             const float* __restrict__ w2,
                                             bf16* __restrict__ w1p,
                                             bf16* __restrict__ w2b,
                                             float* __restrict__ stats) {
    const int tid = threadIdx.x;
    if (blockIdx.z == 8) {
        const int bid = blockIdx.y * 49 + blockIdx.x;        // 0..146
        #pragma unroll
        for (int t = 0; t < 4; ++t) {
            const int idx = bid * 1024 + t * 256 + tid;
            if (idx < C2_ * C2_) {
                const int o  = idx / C2_;
                const int cc = idx - o * C2_;
                const int src = (cc < C_) ? (2 * cc) : (2 * (cc - C_) + 1);
                w1p[idx] = (bf16)w1[o * C2_ + src];
            }
            if (idx < OUT_ * C2_) w2b[idx] = (bf16)w2[idx];
            if (idx < 1152) stats[idx] = 0.f;   // p1s[384] p1q[384] p2s[192] p2q[192]
        }
        return;
    }
    __shared__ float T[64][65];
    const int b  = blockIdx.z;
    const int c0 = blockIdx.y * 64;
    const int n0 = blockIdx.x * 64;
    {   // read coalesced along n: 64 channels x 64 n
        const int nl = tid & 63;
        const int ch = tid >> 6;          // 0..3
        #pragma unroll
        for (int r = 0; r < 16; ++r) {
            const int c = r * 4 + ch;
            T[c][nl] = x[((size_t)b * C_ + (c0 + c)) * N_ + n0 + nl];
        }
    }
    __syncthreads();
    {   // write coalesced along c, bf16x2 per thread
        const int cl = tid & 31;          // channel pair 2cl, 2cl+1
        const int np = tid >> 5;          // 0..7
        #pragma unroll
        for (int p = 0; p < 8; ++p) {
            const int n = p * 8 + np;
            bf16x2 v;
            v[0] = (bf16)T[2 * cl][n];
            v[1] = (bf16)T[2 * cl + 1][n];
            *(bf16x2*)&xt[((size_t)b * N_ + n0 + n) * C_ + c0 + 2 * cl] = v;
        }
    }
}

// ---------------------------------------------------------------------------
// Feats (diff half): d[node][c] = max_k( xt[j_k][c] - xt[i_k][c] )
// 8 nodes per block, 24 threads/node, bf16x8 (16B) gathers. grid M/8, block 192
__global__ __launch_bounds__(192) void k_feats(const bf16* __restrict__ xt,
                                               const int* __restrict__ eidx,
                                               bf16* __restrict__ dbuf) {
    const int t   = threadIdx.x;
    const int nl  = t / 24;                   // 0..7 node within block
    const int cp  = t - nl * 24;              // 0..23 -> channels 8cp..8cp+7
    const int node = blockIdx.x * 8 + nl;
    const int b    = node / N_;
    const int* e0 = eidx + (size_t)node * K_;
    const int* e1 = e0 + (size_t)M_ * K_;
    const bf16* xb = xt + (size_t)b * N_ * C_;
    float mx[8];
    #pragma unroll
    for (int j = 0; j < 8; ++j) mx[j] = -1e30f;
    #pragma unroll
    for (int k = 0; k < K_; ++k) {
        const int j = e0[k];
        const int i = e1[k];
        const bf16x8 aj = *(const bf16x8*)&xb[(size_t)j * C_ + cp * 8];
        const bf16x8 ai = *(const bf16x8*)&xb[(size_t)i * C_ + cp * 8];
        #pragma unroll
        for (int u = 0; u < 8; ++u)
            mx[u] = fmaxf(mx[u], (float)aj[u] - (float)ai[u]);
    }
    bf16x8 o;
    #pragma unroll
    for (int u = 0; u < 8; ++u) o[u] = (bf16)mx[u];
    *(bf16x8*)&dbuf[(size_t)node * C_ + cp * 8] = o;
}

// ---------------------------------------------------------------------------
// GEMM1: h1[m,o] = sum_c [X|D][m,c] * w1p[o,c] + b1[o] -> bf16, fused stats
// 128x128 tile, BK=64, swizzled LDS, 4 waves x (4x4) 16x16x32 frags
// grid (196, 3), block 256
__global__ __launch_bounds__(256) void k_gemm1(const bf16* __restrict__ X,
                                               const bf16* __restrict__ D,
                                               const bf16* __restrict__ Wp,
                                               const float* __restrict__ bias,
                                               bf16* __restrict__ H1,
                                               float* __restrict__ psum,
                                               float* __restrict__ psq) {
    __shared__ bf16 As[128 * 64];
    __shared__ bf16 Bs[128 * 64];
    const int tid  = threadIdx.x;
    const int lane = tid & 63;
    const int wv   = tid >> 6;
    const int l16  = lane & 15;
    const int quad = lane >> 4;
    const int m0   = blockIdx.x * 128;
    const int n0   = blockIdx.y * 128;
    const int wm   = (wv & 1) * 64;
    const int wn   = (wv >> 1) * 64;

    f32x4 acc[4][4] = {};

    for (int kk = 0; kk < C2_; kk += 64) {
        __syncthreads();
        const bf16* asrc = (kk < C_) ? X : D;
        const int   acol = (kk < C_) ? kk : (kk - C_);
        #pragma unroll
        for (int i = 0; i < 4; ++i) {
            const int qb = wv * 256 + i * 64;          // wave-uniform chunk base
            const int q  = qb + lane;
            const int r  = q >> 3;
            const int c8 = (q & 7) ^ (r & 7);          // logical chunk for this slot
            gl_lds16(asrc + (size_t)(m0 + r) * C_ + acol + c8 * 8, &As[qb * 8]);
            gl_lds16(Wp   + (size_t)(n0 + r) * C2_ + kk  + c8 * 8, &Bs[qb * 8]);
        }
        __syncthreads();
        #pragma unroll
        for (int ks = 0; ks < 2; ++ks) {
            bf16x8 af[4], bfr[4];
            #pragma unroll
            for (int f = 0; f < 4; ++f) {
                af[f]  = *(const bf16x8*)&As[sw_off(wm + f * 16 + l16, ks * 4 + quad)];
                bfr[f] = *(const bf16x8*)&Bs[sw_off(wn + f * 16 + l16, ks * 4 + quad)];
            }
            #pragma unroll
            for (int mf = 0; mf < 4; ++mf)
                #pragma unroll
                for (int nf = 0; nf < 4; ++nf)
                    acc[mf][nf] = __builtin_amdgcn_mfma_f32_16x16x32_bf16(
                        af[mf], bfr[nf], acc[mf][nf], 0, 0, 0);
        }
    }

    #pragma unroll
    for (int nf = 0; nf < 4; ++nf) {
        const int col = n0 + wn + nf * 16 + l16;
        const float bv = bias[col];
        float s = 0.f, q = 0.f;
        #pragma unroll
        for (int mf = 0; mf < 4; ++mf) {
            #pragma unroll
            for (int r = 0; r < 4; ++r) {
                const float v = acc[mf][nf][r] + bv;
                s += v; q += v * v;
                H1[(size_t)(m0 + wm + mf * 16 + quad * 4 + r) * C2_ + col] = (bf16)v;
            }
        }
        s += __shfl_xor(s, 16); s += __shfl_xor(s, 32);
        q += __shfl_xor(q, 16); q += __shfl_xor(q, 32);
        if (quad == 0) { atomicAdd(&psum[col], s); atomicAdd(&psq[col], q); }
    }
}

// ---------------------------------------------------------------------------
// Activation: a1 = bf16(gelu(h1*sc + sh)). BN1 params once per block in LDS.
// grid 1176, block 256, 32 elems/thread
__global__ __launch_bounds__(256) void k_act(const bf16* __restrict__ H1,
                                             const float* __restrict__ p1s,
                                             const float* __restrict__ p1q,
                                             const float* __restrict__ g,
                                             const float* __restrict__ beta,
                                             bf16* __restrict__ A1) {
    __shared__ float s_sc[C2_], s_sh[C2_];
    for (int c = threadIdx.x; c < C2_; c += 256) {
        const float mean = p1s[c] * (1.0f / (float)M_);
        const float var  = p1q[c] * (1.0f / (float)M_) - mean * mean;
        const float inv  = rsqrtf(var + EPS_);
        const float scl  = g[c] * inv;
        s_sc[c] = scl;
        s_sh[c] = beta[c] - mean * scl;
    }
    __syncthreads();
    #pragma unroll
    for (int t = 0; t < 4; ++t) {
        const size_t chunk = (size_t)blockIdx.x * 1024 + t * 256 + threadIdx.x;
        const size_t i8 = chunk * 8;
        const int c0 = (int)(i8 % C2_);
        const bf16x8 v = *(const bf16x8*)&H1[i8];
        const float4 sca = *(const float4*)&s_sc[c0];
        const float4 scb = *(const float4*)&s_sc[c0 + 4];
        const float4 sha = *(const float4*)&s_sh[c0];
        const float4 shb = *(const float4*)&s_sh[c0 + 4];
        const float scs[8] = {sca.x, sca.y, sca.z, sca.w, scb.x, scb.y, scb.z, scb.w};
        const float shs[8] = {sha.x, sha.y, sha.z, sha.w, shb.x, shb.y, shb.z, shb.w};
        bf16x8 o;
        #pragma unroll
        for (int j = 0; j < 8; ++j)
            o[j] = (bf16)gelu_f(fmaf((float)v[j], scs[j], shs[j]));
        *(bf16x8*)&A1[i8] = o;
    }
}

// ---------------------------------------------------------------------------
// GEMM2: h2[m,o] = sum_c a1[m,c]*w2[o,c] + b2[o] -> bf16, fused stats
// 128x64 tile, BK=64, swizzled LDS, 4 waves x (4x2) frags
// grid (196, 3), block 256
__global__ __launch_bounds__(256) void k_gemm2(const bf16* __restrict__ A1,
                                               const bf16* __restrict__ W2,
                                               const float* __restrict__ bias,
                                               bf16* __restrict__ H2,
                                               float* __restrict__ psum,
                                               float* __restrict__ psq) {
    __shared__ bf16 As[128 * 64];
    __shared__ bf16 Bs[64 * 64];
    const int tid  = threadIdx.x;
    const int lane = tid & 63;
    const int wv   = tid >> 6;
    const int l16  = lane & 15;
    const int quad = lane >> 4;
    const int m0   = blockIdx.x * 128;
    const int n0   = blockIdx.y * 64;
    const int wm   = (wv & 1) * 64;
    const int wn   = (wv >> 1) * 32;

    f32x4 acc[4][2] = {};

    for (int kk = 0; kk < C2_; kk += 64) {
        __syncthreads();
        #pragma unroll
        for (int i = 0; i < 4; ++i) {
            const int qb = wv * 256 + i * 64;
            const int q  = qb + lane;
            const int r  = q >> 3;
            const int c8 = (q & 7) ^ (r & 7);
            gl_lds16(A1 + (size_t)(m0 + r) * C2_ + kk + c8 * 8, &As[qb * 8]);
        }
        #pragma unroll
        for (int i = 0; i < 2; ++i) {
            const int qb = wv * 128 + i * 64;
            const int q  = qb + lane;
            const int r  = q >> 3;
            const int c8 = (q & 7) ^ (r & 7);
            gl_lds16(W2 + (size_t)(n0 + r) * C2_ + kk + c8 * 8, &Bs[qb * 8]);
        }
        __syncthreads();
        #pragma unroll
        for (int ks = 0; ks < 2; ++ks) {
            bf16x8 af[4], bfr[2];
            #pragma unroll
            for (int f = 0; f < 4; ++f)
                af[f] = *(const bf16x8*)&As[sw_off(wm + f * 16 + l16, ks * 4 + quad)];
            #pragma unroll
            for (int f = 0; f < 2; ++f)
                bfr[f] = *(const bf16x8*)&Bs[sw_off(wn + f * 16 + l16, ks * 4 + quad)];
            #pragma unroll
            for (int mf = 0; mf < 4; ++mf)
                #pragma unroll
                for (int nf = 0; nf < 2; ++nf)
                    acc[mf][nf] = __builtin_amdgcn_mfma_f32_16x16x32_bf16(
                        af[mf], bfr[nf], acc[mf][nf], 0, 0, 0);
        }
    }

    #pragma unroll
    for (int nf = 0; nf < 2; ++nf) {
        const int col = n0 + wn + nf * 16 + l16;
        const float bv = bias[col];
        float s = 0.f, q = 0.f;
        #pragma unroll
        for (int mf = 0; mf < 4; ++mf) {
            #pragma unroll
            for (int r = 0; r < 4; ++r) {
                const float v = acc[mf][nf][r] + bv;
                s += v; q += v * v;
                H2[(size_t)(m0 + wm + mf * 16 + quad * 4 + r) * OUT_ + col] = (bf16)v;
            }
        }
        s += __shfl_xor(s, 16); s += __shfl_xor(s, 32);
        q += __shfl_xor(q, 16); q += __shfl_xor(q, 32);
        if (quad == 0) { atomicAdd(&psum[col], s); atomicAdd(&psq[col], q); }
    }
}

// ---------------------------------------------------------------------------
// Output: BN2+GELU + transpose [M,OUT] bf16 -> [B,OUT,N] fp32, bf16x2 reads
// grid (N/64, OUT/32, B), block 256
__global__ __launch_bounds__(256) void k_out(const bf16* __restrict__ H2,
                                             const float* __restrict__ p2s,
                                             const float* __restrict__ p2q,
                                             const float* __restrict__ g,
                                             const float* __restrict__ beta,
                                             float* __restrict__ out) {
    __shared__ float T[64][33];
    const int b  = blockIdx.z;
    const int o0 = blockIdx.y * 32;
    const int n0 = blockIdx.x * 64;
    const int tid = threadIdx.x;
    {   // read coalesced along o (bf16x2), apply BN+GELU
        const int ol2 = tid & 15;         // o pair: o0+2*ol2, +1
        const int nl  = tid >> 4;         // 0..15
        const int o   = o0 + 2 * ol2;
        const float mean0  = p2s[o]     * (1.0f / (float)M_);
        const float var0   = p2q[o]     * (1.0f / (float)M_) - mean0 * mean0;
        const float scale0 = g[o] * rsqrtf(var0 + EPS_);
        const float shift0 = beta[o] - mean0 * scale0;
        const float mean1  = p2s[o + 1] * (1.0f / (float)M_);
        const float var1   = p2q[o + 1] * (1.0f / (float)M_) - mean1 * mean1;
        const float scale1 = g[o + 1] * rsqrtf(var1 + EPS_);
        const float shift1 = beta[o + 1] - mean1 * scale1;
        #pragma unroll
        for (int r = 0; r < 4; ++r) {
            const int n = nl + r * 16;
            const bf16x2 h = *(const bf16x2*)&H2[((size_t)b * N_ + n0 + n) * OUT_ + o];
            T[n][2 * ol2]     = gelu_f(fmaf((float)h[0], scale0, shift0));
            T[n][2 * ol2 + 1] = gelu_f(fmaf((float)h[1], scale1, shift1));
        }
    }
    __syncthreads();
    {   // write coalesced along n
        const int nl = tid & 63;
        const int ol = tid >> 6;          // 0..3
        #pragma unroll
        for (int r = 0; r < 8; ++r) {
            const int o = ol + r * 4;
            out[((size_t)b * OUT_ + o0 + o) * N_ + n0 + nl] = T[nl][o];
        }
    }
}

// ---------------------------------------------------------------------------
extern "C" void kernel_launch(void* const* d_in, const int* in_sizes, int n_in,
                              void* d_out, int out_size, void* d_ws, size_t ws_size,
                              hipStream_t stream) {
    const float* x     = (const float*)d_in[0];
    const int*   eidx  = (const int*)  d_in[1];
    const float* w1    = (const float*)d_in[2];
    const float* b1    = (const float*)d_in[3];
    const float* g1    = (const float*)d_in[4];
    const float* beta1 = (const float*)d_in[5];
    const float* w2    = (const float*)d_in[6];
    const float* b2    = (const float*)d_in[7];
    const float* g2    = (const float*)d_in[8];
    const float* beta2 = (const float*)d_in[9];
    float* out = (float*)d_out;

    char* ws = (char*)d_ws;
    size_t off = 0;
    bf16*  xt    = (bf16*)(ws + off); off += (size_t)M_ * C_  * sizeof(bf16);
    bf16*  dbuf  = (bf16*)(ws + off); off += (size_t)M_ * C_  * sizeof(bf16);
    bf16*  h1    = (bf16*)(ws + off); off += (size_t)M_ * C2_ * sizeof(bf16);
    bf16*  a1    = (bf16*)(ws + off); off += (size_t)M_ * C2_ * sizeof(bf16);
    bf16*  h2    = (bf16*)(ws + off); off += (size_t)M_ * OUT_ * sizeof(bf16);
    bf16*  w1p   = (bf16*)(ws + off); off += (size_t)C2_ * C2_ * sizeof(bf16);
    bf16*  w2b   = (bf16*)(ws + off); off += (size_t)OUT_ * C2_ * sizeof(bf16);
    float* stats = (float*)(ws + off); off += 1152 * sizeof(float);
    float* p1s = stats;        // 384
    float* p1q = stats + 384;  // 384
    float* p2s = stats + 768;  // 192
    float* p2q = stats + 960;  // 192

    k_pre<<<dim3(49, 3, 9), 256, 0, stream>>>(x, xt, w1, w2, w1p, w2b, stats);
    k_feats<<<M_ / 8, 192, 0, stream>>>(xt, eidx, dbuf);
    k_gemm1<<<dim3(M_ / 128, C2_ / 128), 256, 0, stream>>>(xt, dbuf, w1p, b1, h1, p1s, p1q);
    k_act<<<1176, 256, 0, stream>>>(h1, p1s, p1q, g1, beta1, a1);
    k_gemm2<<<dim3(M_ / 128, OUT_ / 64), 256, 0, stream>>>(a1, w2b, b2, h2, p2s, p2q);
    k_out<<<dim3(N_ / 64, OUT_ / 32, B_), 256, 0, stream>>>(h2, p2s, p2q, g2, beta2, out);
}

// Round 9
// 174.582 us; speedup vs baseline: 1.1296x; 1.0055x over previous
//
#include <hip/hip_runtime.h>
#include <math.h>

// Problem constants
#define B_    8
#define C_    192
#define N_    3136          // H*W
#define K_    9
#define C2_   384
#define OUT_  192
#define M_    (B_ * N_)     // 25088 rows
#define EPS_  1e-5f

typedef __bf16 bf16;
typedef __bf16 bf16x2 __attribute__((ext_vector_type(2)));
typedef __bf16 bf16x8 __attribute__((ext_vector_type(8)));
typedef float  f32x4  __attribute__((ext_vector_type(4)));

__device__ __forceinline__ float gelu_f(float x) {
    return 0.5f * x * (1.0f + erff(x * 0.70710678118654752440f));
}

// async global->LDS, 16B per lane; lds base must be wave-uniform
__device__ __forceinline__ void gl_lds16(const void* g, void* l) {
    __builtin_amdgcn_global_load_lds(
        (const __attribute__((address_space(1))) unsigned int*)g,
        (__attribute__((address_space(3))) unsigned int*)l, 16, 0, 0);
}

// Swizzled LDS tile layout: tile is [rows][64] bf16, stored as 16B chunks.
// Logical chunk (r, c8) lives at slot r*8 + (c8 ^ (r&7)); element offset slot*8.
__device__ __forceinline__ int sw_off(int r, int c8) {
    return (r * 8 + (c8 ^ (r & 7))) * 8;
}

// ---------------------------------------------------------------------------
// k_pre: z<8 -> transpose x fp32 [B,C,N] -> xt bf16 [B,N,C]  (64x64 tiles,
//        float4 global reads = 1 KiB/wave-instr, bf16x8 stores)
//        z==8 -> cast+permute w1 -> w1p, cast w2 -> w2b, zero stats
// grid (49, 3, 9), block 256
__global__ __launch_bounds__(256) void k_pre(const float* __restrict__ x,
                                             bf16* __restrict__ xt,
                                             const float* __restrict__ w1,
                                             const float* __restrict__ w2,
                                             bf16* __restrict__ w1p,
                                             bf16* __restrict__ w2b,
                                             float* __restrict__ stats) {
    const int tid = threadIdx.x;
    if (blockIdx.z == 8) {
        const int bid = blockIdx.y * 49 + blockIdx.x;        // 0..146
        #pragma unroll
        for (int t = 0; t < 4; ++t) {
            const int idx = bid * 1024 + t * 256 + tid;
            if (idx < C2_ * C2_) {
                const int o  = idx / C2_;
                const int cc = idx - o * C2_;
                const int src = (cc < C_) ? (2 * cc) : (2 * (cc - C_) + 1);
                w1p[idx] = (bf16)w1[o * C2_ + src];
            }
            if (idx < OUT_ * C2_) w2b[idx] = (bf16)w2[idx];
            if (idx < 1152) stats[idx] = 0.f;   // p1s[384] p1q[384] p2s[192] p2q[192]
        }
        return;
    }
    __shared__ float T[64][68];   // stride 68 floats = 272 B -> 16B-aligned cols
    const int b  = blockIdx.z;
    const int c0 = blockIdx.y * 64;
    const int n0 = blockIdx.x * 64;
    {   // read: float4 along n. thread: q = n-quad 0..15, rg = c row-group 0..15
        const int q  = tid & 15;
        const int rg = tid >> 4;
        #pragma unroll
        for (int r = 0; r < 4; ++r) {
            const int c = rg + r * 16;
            const float4 v = *(const float4*)&x[((size_t)b * C_ + (c0 + c)) * N_ + n0 + 4 * q];
            *(float4*)&T[c][4 * q] = v;
        }
    }
    __syncthreads();
    {   // write: bf16x8 per store (8 channels). oct = c-octet 0..7, nn = 0..31
        const int oct = tid & 7;
        const int nn  = tid >> 3;
        #pragma unroll
        for (int p = 0; p < 2; ++p) {
            const int n = nn + p * 32;
            bf16x8 v;
            #pragma unroll
            for (int j = 0; j < 8; ++j) v[j] = (bf16)T[8 * oct + j][n];
            *(bf16x8*)&xt[((size_t)b * N_ + n0 + n) * C_ + c0 + 8 * oct] = v;
        }
    }
}

// ---------------------------------------------------------------------------
// Feats (diff half): d[node][c] = max_k( xt[j_k][c] - xt[i_k][c] )
// 8 nodes per block, 24 threads/node, bf16x8 (16B) gathers. grid M/8, block 192
__global__ __launch_bounds__(192) void k_feats(const bf16* __restrict__ xt,
                                               const int* __restrict__ eidx,
                                               bf16* __restrict__ dbuf) {
    const int t   = threadIdx.x;
    const int nl  = t / 24;                   // 0..7 node within block
    const int cp  = t - nl * 24;              // 0..23 -> channels 8cp..8cp+7
    const int node = blockIdx.x * 8 + nl;
    const int b    = node / N_;
    const int* e0 = eidx + (size_t)node * K_;
    const int* e1 = e0 + (size_t)M_ * K_;
    const bf16* xb = xt + (size_t)b * N_ * C_;
    float mx[8];
    #pragma unroll
    for (int j = 0; j < 8; ++j) mx[j] = -1e30f;
    #pragma unroll
    for (int k = 0; k < K_; ++k) {
        const int j = e0[k];
        const int i = e1[k];
        const bf16x8 aj = *(const bf16x8*)&xb[(size_t)j * C_ + cp * 8];
        const bf16x8 ai = *(const bf16x8*)&xb[(size_t)i * C_ + cp * 8];
        #pragma unroll
        for (int u = 0; u < 8; ++u)
            mx[u] = fmaxf(mx[u], (float)aj[u] - (float)ai[u]);
    }
    bf16x8 o;
    #pragma unroll
    for (int u = 0; u < 8; ++u) o[u] = (bf16)mx[u];
    *(bf16x8*)&dbuf[(size_t)node * C_ + cp * 8] = o;
}

// ---------------------------------------------------------------------------
// GEMM1: h1[m,o] = sum_c [X|D][m,c] * w1p[o,c] + b1[o] -> bf16, fused stats
// 128x128 tile, BK=64, swizzled LDS, 4 waves x (4x4) 16x16x32 frags
// grid (196, 3), block 256
__global__ __launch_bounds__(256) void k_gemm1(const bf16* __restrict__ X,
                                               const bf16* __restrict__ D,
                                               const bf16* __restrict__ Wp,
                                               const float* __restrict__ bias,
                                               bf16* __restrict__ H1,
                                               float* __restrict__ psum,
                                               float* __restrict__ psq) {
    __shared__ bf16 As[128 * 64];
    __shared__ bf16 Bs[128 * 64];
    const int tid  = threadIdx.x;
    const int lane = tid & 63;
    const int wv   = tid >> 6;
    const int l16  = lane & 15;
    const int quad = lane >> 4;
    const int m0   = blockIdx.x * 128;
    const int n0   = blockIdx.y * 128;
    const int wm   = (wv & 1) * 64;
    const int wn   = (wv >> 1) * 64;

    f32x4 acc[4][4] = {};

    for (int kk = 0; kk < C2_; kk += 64) {
        __syncthreads();
        const bf16* asrc = (kk < C_) ? X : D;
        const int   acol = (kk < C_) ? kk : (kk - C_);
        #pragma unroll
        for (int i = 0; i < 4; ++i) {
            const int qb = wv * 256 + i * 64;          // wave-uniform chunk base
            const int q  = qb + lane;
            const int r  = q >> 3;
            const int c8 = (q & 7) ^ (r & 7);          // logical chunk for this slot
            gl_lds16(asrc + (size_t)(m0 + r) * C_ + acol + c8 * 8, &As[qb * 8]);
            gl_lds16(Wp   + (size_t)(n0 + r) * C2_ + kk  + c8 * 8, &Bs[qb * 8]);
        }
        __syncthreads();
        #pragma unroll
        for (int ks = 0; ks < 2; ++ks) {
            bf16x8 af[4], bfr[4];
            #pragma unroll
            for (int f = 0; f < 4; ++f) {
                af[f]  = *(const bf16x8*)&As[sw_off(wm + f * 16 + l16, ks * 4 + quad)];
                bfr[f] = *(const bf16x8*)&Bs[sw_off(wn + f * 16 + l16, ks * 4 + quad)];
            }
            #pragma unroll
            for (int mf = 0; mf < 4; ++mf)
                #pragma unroll
                for (int nf = 0; nf < 4; ++nf)
                    acc[mf][nf] = __builtin_amdgcn_mfma_f32_16x16x32_bf16(
                        af[mf], bfr[nf], acc[mf][nf], 0, 0, 0);
        }
    }

    #pragma unroll
    for (int nf = 0; nf < 4; ++nf) {
        const int col = n0 + wn + nf * 16 + l16;
        const float bv = bias[col];
        float s = 0.f, q = 0.f;
        #pragma unroll
        for (int mf = 0; mf < 4; ++mf) {
            #pragma unroll
            for (int r = 0; r < 4; ++r) {
                const float v = acc[mf][nf][r] + bv;
                s += v; q += v * v;
                H1[(size_t)(m0 + wm + mf * 16 + quad * 4 + r) * C2_ + col] = (bf16)v;
            }
        }
        s += __shfl_xor(s, 16); s += __shfl_xor(s, 32);
        q += __shfl_xor(q, 16); q += __shfl_xor(q, 32);
        if (quad == 0) { atomicAdd(&psum[col], s); atomicAdd(&psq[col], q); }
    }
}

// ---------------------------------------------------------------------------
// Activation: a1 = bf16(gelu(h1*sc + sh)). BN1 params once per block in LDS.
// grid 1176, block 256, 32 elems/thread
__global__ __launch_bounds__(256) void k_act(const bf16* __restrict__ H1,
                                             const float* __restrict__ p1s,
                                             const float* __restrict__ p1q,
                                             const float* __restrict__ g,
                                             const float* __restrict__ beta,
                                             bf16* __restrict__ A1) {
    __shared__ float s_sc[C2_], s_sh[C2_];
    for (int c = threadIdx.x; c < C2_; c += 256) {
        const float mean = p1s[c] * (1.0f / (float)M_);
        const float var  = p1q[c] * (1.0f / (float)M_) - mean * mean;
        const float inv  = rsqrtf(var + EPS_);
        const float scl  = g[c] * inv;
        s_sc[c] = scl;
        s_sh[c] = beta[c] - mean * scl;
    }
    __syncthreads();
    #pragma unroll
    for (int t = 0; t < 4; ++t) {
        const size_t chunk = (size_t)blockIdx.x * 1024 + t * 256 + threadIdx.x;
        const size_t i8 = chunk * 8;
        const int c0 = (int)(i8 % C2_);
        const bf16x8 v = *(const bf16x8*)&H1[i8];
        const float4 sca = *(const float4*)&s_sc[c0];
        const float4 scb = *(const float4*)&s_sc[c0 + 4];
        const float4 sha = *(const float4*)&s_sh[c0];
        const float4 shb = *(const float4*)&s_sh[c0 + 4];
        const float scs[8] = {sca.x, sca.y, sca.z, sca.w, scb.x, scb.y, scb.z, scb.w};
        const float shs[8] = {sha.x, sha.y, sha.z, sha.w, shb.x, shb.y, shb.z, shb.w};
        bf16x8 o;
        #pragma unroll
        for (int j = 0; j < 8; ++j)
            o[j] = (bf16)gelu_f(fmaf((float)v[j], scs[j], shs[j]));
        *(bf16x8*)&A1[i8] = o;
    }
}

// ---------------------------------------------------------------------------
// GEMM2: h2[m,o] = sum_c a1[m,c]*w2[o,c] + b2[o] -> bf16, fused stats
// 128x64 tile, BK=64, swizzled LDS, 4 waves x (4x2) frags
// grid (196, 3), block 256
__global__ __launch_bounds__(256) void k_gemm2(const bf16* __restrict__ A1,
                                               const bf16* __restrict__ W2,
                                               const float* __restrict__ bias,
                                               bf16* __restrict__ H2,
                                               float* __restrict__ psum,
                                               float* __restrict__ psq) {
    __shared__ bf16 As[128 * 64];
    __shared__ bf16 Bs[64 * 64];
    const int tid  = threadIdx.x;
    const int lane = tid & 63;
    const int wv   = tid >> 6;
    const int l16  = lane & 15;
    const int quad = lane >> 4;
    const int m0   = blockIdx.x * 128;
    const int n0   = blockIdx.y * 64;
    const int wm   = (wv & 1) * 64;
    const int wn   = (wv >> 1) * 32;

    f32x4 acc[4][2] = {};

    for (int kk = 0; kk < C2_; kk += 64) {
        __syncthreads();
        #pragma unroll
        for (int i = 0; i < 4; ++i) {
            const int qb = wv * 256 + i * 64;
            const int q  = qb + lane;
            const int r  = q >> 3;
            const int c8 = (q & 7) ^ (r & 7);
            gl_lds16(A1 + (size_t)(m0 + r) * C2_ + kk + c8 * 8, &As[qb * 8]);
        }
        #pragma unroll
        for (int i = 0; i < 2; ++i) {
            const int qb = wv * 128 + i * 64;
            const int q  = qb + lane;
            const int r  = q >> 3;
            const int c8 = (q & 7) ^ (r & 7);
            gl_lds16(W2 + (size_t)(n0 + r) * C2_ + kk + c8 * 8, &Bs[qb * 8]);
        }
        __syncthreads();
        #pragma unroll
        for (int ks = 0; ks < 2; ++ks) {
            bf16x8 af[4], bfr[2];
            #pragma unroll
            for (int f = 0; f < 4; ++f)
                af[f] = *(const bf16x8*)&As[sw_off(wm + f * 16 + l16, ks * 4 + quad)];
            #pragma unroll
            for (int f = 0; f < 2; ++f)
                bfr[f] = *(const bf16x8*)&Bs[sw_off(wn + f * 16 + l16, ks * 4 + quad)];
            #pragma unroll
            for (int mf = 0; mf < 4; ++mf)
                #pragma unroll
                for (int nf = 0; nf < 2; ++nf)
                    acc[mf][nf] = __builtin_amdgcn_mfma_f32_16x16x32_bf16(
                        af[mf], bfr[nf], acc[mf][nf], 0, 0, 0);
        }
    }

    #pragma unroll
    for (int nf = 0; nf < 2; ++nf) {
        const int col = n0 + wn + nf * 16 + l16;
        const float bv = bias[col];
        float s = 0.f, q = 0.f;
        #pragma unroll
        for (int mf = 0; mf < 4; ++mf) {
            #pragma unroll
            for (int r = 0; r < 4; ++r) {
                const float v = acc[mf][nf][r] + bv;
                s += v; q += v * v;
                H2[(size_t)(m0 + wm + mf * 16 + quad * 4 + r) * OUT_ + col] = (bf16)v;
            }
        }
        s += __shfl_xor(s, 16); s += __shfl_xor(s, 32);
        q += __shfl_xor(q, 16); q += __shfl_xor(q, 32);
        if (quad == 0) { atomicAdd(&psum[col], s); atomicAdd(&psq[col], q); }
    }
}

// ---------------------------------------------------------------------------
// Output: BN2+GELU + transpose [M,OUT] bf16 -> [B,OUT,N] fp32
// bf16x2 strided reads; float4 coalesced writes (1 KiB/wave-instr)
// grid (N/64, OUT/32, B), block 256
__global__ __launch_bounds__(256) void k_out(const bf16* __restrict__ H2,
                                             const float* __restrict__ p2s,
                                             const float* __restrict__ p2q,
                                             const float* __restrict__ g,
                                             const float* __restrict__ beta,
                                             float* __restrict__ out) {
    __shared__ float T[64][33];
    const int b  = blockIdx.z;
    const int o0 = blockIdx.y * 32;
    const int n0 = blockIdx.x * 64;
    const int tid = threadIdx.x;
    {   // read coalesced along o (bf16x2), apply BN+GELU
        const int ol2 = tid & 15;         // o pair: o0+2*ol2, +1
        const int nl  = tid >> 4;         // 0..15
        const int o   = o0 + 2 * ol2;
        const float mean0  = p2s[o]     * (1.0f / (float)M_);
        const float var0   = p2q[o]     * (1.0f / (float)M_) - mean0 * mean0;
        const float scale0 = g[o] * rsqrtf(var0 + EPS_);
        const float shift0 = beta[o] - mean0 * scale0;
        const float mean1  = p2s[o + 1] * (1.0f / (float)M_);
        const float var1   = p2q[o + 1] * (1.0f / (float)M_) - mean1 * mean1;
        const float scale1 = g[o + 1] * rsqrtf(var1 + EPS_);
        const float shift1 = beta[o + 1] - mean1 * scale1;
        #pragma unroll
        for (int r = 0; r < 4; ++r) {
            const int n = nl + r * 16;
            const bf16x2 h = *(const bf16x2*)&H2[((size_t)b * N_ + n0 + n) * OUT_ + o];
            T[n][2 * ol2]     = gelu_f(fmaf((float)h[0], scale0, shift0));
            T[n][2 * ol2 + 1] = gelu_f(fmaf((float)h[1], scale1, shift1));
        }
    }
    __syncthreads();
    {   // write: float4 along n. u = n-quad 0..15, o = 0..15 then +16
        const int u  = tid & 15;
        const int ob = tid >> 4;          // 0..15
        #pragma unroll
        for (int p = 0; p < 2; ++p) {
            const int o = ob + p * 16;
            float4 v;
            v.x = T[4 * u + 0][o];
            v.y = T[4 * u + 1][o];
            v.z = T[4 * u + 2][o];
            v.w = T[4 * u + 3][o];
            *(float4*)&out[((size_t)b * OUT_ + o0 + o) * N_ + n0 + 4 * u] = v;
        }
    }
}

// ---------------------------------------------------------------------------
extern "C" void kernel_launch(void* const* d_in, const int* in_sizes, int n_in,
                              void* d_out, int out_size, void* d_ws, size_t ws_size,
                              hipStream_t stream) {
    const float* x     = (const float*)d_in[0];
    const int*   eidx  = (const int*)  d_in[1];
    const float* w1    = (const float*)d_in[2];
    const float* b1    = (const float*)d_in[3];
    const float* g1    = (const float*)d_in[4];
    const float* beta1 = (const float*)d_in[5];
    const float* w2    = (const float*)d_in[6];
    const float* b2    = (const float*)d_in[7];
    const float* g2    = (const float*)d_in[8];
    const float* beta2 = (const float*)d_in[9];
    float* out = (float*)d_out;

    char* ws = (char*)d_ws;
    size_t off = 0;
    bf16*  xt    = (bf16*)(ws + off); off += (size_t)M_ * C_  * sizeof(bf16);
    bf16*  dbuf  = (bf16*)(ws + off); off += (size_t)M_ * C_  * sizeof(bf16);
    bf16*  h1    = (bf16*)(ws + off); off += (size_t)M_ * C2_ * sizeof(bf16);
    bf16*  a1    = (bf16*)(ws + off); off += (size_t)M_ * C2_ * sizeof(bf16);
    bf16*  h2    = (bf16*)(ws + off); off += (size_t)M_ * OUT_ * sizeof(bf16);
    bf16*  w1p   = (bf16*)(ws + off); off += (size_t)C2_ * C2_ * sizeof(bf16);
    bf16*  w2b   = (bf16*)(ws + off); off += (size_t)OUT_ * C2_ * sizeof(bf16);
    float* stats = (float*)(ws + off); off += 1152 * sizeof(float);
    float* p1s = stats;        // 384
    float* p1q = stats + 384;  // 384
    float* p2s = stats + 768;  // 192
    float* p2q = stats + 960;  // 192

    k_pre<<<dim3(49, 3, 9), 256, 0, stream>>>(x, xt, w1, w2, w1p, w2b, stats);
    k_feats<<<M_ / 8, 192, 0, stream>>>(xt, eidx, dbuf);
    k_gemm1<<<dim3(M_ / 128, C2_ / 128), 256, 0, stream>>>(xt, dbuf, w1p, b1, h1, p1s, p1q);
    k_act<<<1176, 256, 0, stream>>>(h1, p1s, p1q, g1, beta1, a1);
    k_gemm2<<<dim3(M_ / 128, OUT_ / 64), 256, 0, stream>>>(a1, w2b, b2, h2, p2s, p2q);
    k_out<<<dim3(N_ / 64, OUT_ / 32, B_), 256, 0, stream>>>(h2, p2s, p2q, g2, beta2, out);
}

// Round 10
// 174.118 us; speedup vs baseline: 1.1327x; 1.0027x over previous
//
#include <hip/hip_runtime.h>
#include <math.h>

// Problem constants
#define B_    8
#define C_    192
#define N_    3136          // H*W
#define K_    9
#define C2_   384
#define OUT_  192
#define M_    (B_ * N_)     // 25088 rows
#define EPS_  1e-5f

typedef __bf16 bf16;
typedef __bf16 bf16x2 __attribute__((ext_vector_type(2)));
typedef __bf16 bf16x8 __attribute__((ext_vector_type(8)));
typedef float  f32x4  __attribute__((ext_vector_type(4)));

__device__ __forceinline__ float gelu_f(float x) {
    return 0.5f * x * (1.0f + erff(x * 0.70710678118654752440f));
}

// async global->LDS, 16B per lane; lds base must be wave-uniform
__device__ __forceinline__ void gl_lds16(const void* g, void* l) {
    __builtin_amdgcn_global_load_lds(
        (const __attribute__((address_space(1))) unsigned int*)g,
        (__attribute__((address_space(3))) unsigned int*)l, 16, 0, 0);
}

// Swizzled LDS tile layout: tile is [rows][64] bf16, stored as 16B chunks.
// Logical chunk (r, c8) lives at slot r*8 + (c8 ^ (r&7)); element offset slot*8.
__device__ __forceinline__ int sw_off(int r, int c8) {
    return (r * 8 + (c8 ^ (r & 7))) * 8;
}

// ---------------------------------------------------------------------------
// k_pre: z<8 -> transpose x fp32 [B,C,N] -> xt bf16 [B,N,C]  (64x64 tiles,
//        float4 global reads = 1 KiB/wave-instr, bf16x8 stores)
//        z==8 -> cast+permute w1 -> w1p, cast w2 -> w2b, zero stats
// grid (49, 3, 9), block 256
__global__ __launch_bounds__(256) void k_pre(const float* __restrict__ x,
                                             bf16* __restrict__ xt,
                                             const float* __restrict__ w1,
                                             const float* __restrict__ w2,
                                             bf16* __restrict__ w1p,
                                             bf16* __restrict__ w2b,
                                             float* __restrict__ stats) {
    const int tid = threadIdx.x;
    if (blockIdx.z == 8) {
        const int bid = blockIdx.y * 49 + blockIdx.x;        // 0..146
        #pragma unroll
        for (int t = 0; t < 4; ++t) {
            const int idx = bid * 1024 + t * 256 + tid;
            if (idx < C2_ * C2_) {
                const int o  = idx / C2_;
                const int cc = idx - o * C2_;
                const int src = (cc < C_) ? (2 * cc) : (2 * (cc - C_) + 1);
                w1p[idx] = (bf16)w1[o * C2_ + src];
            }
            if (idx < OUT_ * C2_) w2b[idx] = (bf16)w2[idx];
            if (idx < 1152) stats[idx] = 0.f;   // p1s[384] p1q[384] p2s[192] p2q[192]
        }
        return;
    }
    __shared__ float T[64][68];   // stride 68 floats = 272 B -> 16B-aligned cols
    const int b  = blockIdx.z;
    const int c0 = blockIdx.y * 64;
    const int n0 = blockIdx.x * 64;
    {   // read: float4 along n. thread: q = n-quad 0..15, rg = c row-group 0..15
        const int q  = tid & 15;
        const int rg = tid >> 4;
        #pragma unroll
        for (int r = 0; r < 4; ++r) {
            const int c = rg + r * 16;
            const float4 v = *(const float4*)&x[((size_t)b * C_ + (c0 + c)) * N_ + n0 + 4 * q];
            *(float4*)&T[c][4 * q] = v;
        }
    }
    __syncthreads();
    {   // write: bf16x8 per store (8 channels). oct = c-octet 0..7, nn = 0..31
        const int oct = tid & 7;
        const int nn  = tid >> 3;
        #pragma unroll
        for (int p = 0; p < 2; ++p) {
            const int n = nn + p * 32;
            bf16x8 v;
            #pragma unroll
            for (int j = 0; j < 8; ++j) v[j] = (bf16)T[8 * oct + j][n];
            *(bf16x8*)&xt[((size_t)b * N_ + n0 + n) * C_ + c0 + 8 * oct] = v;
        }
    }
}

// ---------------------------------------------------------------------------
// Feats (diff half): d[node][c] = max_k( xt[j_k][c] - xt[i_k][c] )
// 8 nodes per block, 24 threads/node, bf16x8 (16B) gathers.
// Edge indices LDS-staged once per block (kills 24x-redundant global loads).
// grid M/8, block 192
__global__ __launch_bounds__(192) void k_feats(const bf16* __restrict__ xt,
                                               const int* __restrict__ eidx,
                                               bf16* __restrict__ dbuf) {
    __shared__ int sj[8][9], si[8][9];
    const int t = threadIdx.x;
    if (t < 144) {
        const int nn = t / 18;            // node 0..7
        const int r  = t - nn * 18;       // 0..17
        const int node = blockIdx.x * 8 + nn;
        if (r < 9) sj[nn][r]     = eidx[(size_t)node * K_ + r];
        else       si[nn][r - 9] = eidx[(size_t)M_ * K_ + (size_t)node * K_ + (r - 9)];
    }
    __syncthreads();
    const int nl  = t / 24;                   // 0..7 node within block
    const int cp  = t - nl * 24;              // 0..23 -> channels 8cp..8cp+7
    const int node = blockIdx.x * 8 + nl;
    const int b    = node / N_;
    const bf16* xb = xt + (size_t)b * N_ * C_;
    float mx[8];
    #pragma unroll
    for (int j = 0; j < 8; ++j) mx[j] = -1e30f;
    #pragma unroll
    for (int k = 0; k < K_; ++k) {
        const int j = sj[nl][k];          // same-address LDS broadcast (free)
        const int i = si[nl][k];
        const bf16x8 aj = *(const bf16x8*)&xb[(size_t)j * C_ + cp * 8];
        const bf16x8 ai = *(const bf16x8*)&xb[(size_t)i * C_ + cp * 8];
        #pragma unroll
        for (int u = 0; u < 8; ++u)
            mx[u] = fmaxf(mx[u], (float)aj[u] - (float)ai[u]);
    }
    bf16x8 o;
    #pragma unroll
    for (int u = 0; u < 8; ++u) o[u] = (bf16)mx[u];
    *(bf16x8*)&dbuf[(size_t)node * C_ + cp * 8] = o;
}

// ---------------------------------------------------------------------------
// GEMM1: h1[m,o] = sum_c [X|D][m,c] * w1p[o,c] + b1[o] -> bf16, fused stats
// 128x128 tile, BK=64, swizzled LDS, 4 waves x (4x4) 16x16x32 frags
// grid (196, 3), block 256
__global__ __launch_bounds__(256) void k_gemm1(const bf16* __restrict__ X,
                                               const bf16* __restrict__ D,
                                               const bf16* __restrict__ Wp,
                                               const float* __restrict__ bias,
                                               bf16* __restrict__ H1,
                                               float* __restrict__ psum,
                                               float* __restrict__ psq) {
    __shared__ bf16 As[128 * 64];
    __shared__ bf16 Bs[128 * 64];
    const int tid  = threadIdx.x;
    const int lane = tid & 63;
    const int wv   = tid >> 6;
    const int l16  = lane & 15;
    const int quad = lane >> 4;
    const int m0   = blockIdx.x * 128;
    const int n0   = blockIdx.y * 128;
    const int wm   = (wv & 1) * 64;
    const int wn   = (wv >> 1) * 64;

    f32x4 acc[4][4] = {};

    for (int kk = 0; kk < C2_; kk += 64) {
        __syncthreads();
        const bf16* asrc = (kk < C_) ? X : D;
        const int   acol = (kk < C_) ? kk : (kk - C_);
        #pragma unroll
        for (int i = 0; i < 4; ++i) {
            const int qb = wv * 256 + i * 64;          // wave-uniform chunk base
            const int q  = qb + lane;
            const int r  = q >> 3;
            const int c8 = (q & 7) ^ (r & 7);          // logical chunk for this slot
            gl_lds16(asrc + (size_t)(m0 + r) * C_ + acol + c8 * 8, &As[qb * 8]);
            gl_lds16(Wp   + (size_t)(n0 + r) * C2_ + kk  + c8 * 8, &Bs[qb * 8]);
        }
        __syncthreads();
        #pragma unroll
        for (int ks = 0; ks < 2; ++ks) {
            bf16x8 af[4], bfr[4];
            #pragma unroll
            for (int f = 0; f < 4; ++f) {
                af[f]  = *(const bf16x8*)&As[sw_off(wm + f * 16 + l16, ks * 4 + quad)];
                bfr[f] = *(const bf16x8*)&Bs[sw_off(wn + f * 16 + l16, ks * 4 + quad)];
            }
            #pragma unroll
            for (int mf = 0; mf < 4; ++mf)
                #pragma unroll
                for (int nf = 0; nf < 4; ++nf)
                    acc[mf][nf] = __builtin_amdgcn_mfma_f32_16x16x32_bf16(
                        af[mf], bfr[nf], acc[mf][nf], 0, 0, 0);
        }
    }

    #pragma unroll
    for (int nf = 0; nf < 4; ++nf) {
        const int col = n0 + wn + nf * 16 + l16;
        const float bv = bias[col];
        float s = 0.f, q = 0.f;
        #pragma unroll
        for (int mf = 0; mf < 4; ++mf) {
            #pragma unroll
            for (int r = 0; r < 4; ++r) {
                const float v = acc[mf][nf][r] + bv;
                s += v; q += v * v;
                H1[(size_t)(m0 + wm + mf * 16 + quad * 4 + r) * C2_ + col] = (bf16)v;
            }
        }
        s += __shfl_xor(s, 16); s += __shfl_xor(s, 32);
        q += __shfl_xor(q, 16); q += __shfl_xor(q, 32);
        if (quad == 0) { atomicAdd(&psum[col], s); atomicAdd(&psq[col], q); }
    }
}

// ---------------------------------------------------------------------------
// Activation: a1 = bf16(gelu(h1*sc + sh)). BN1 params once per block in LDS.
// grid 1176, block 256, 32 elems/thread
__global__ __launch_bounds__(256) void k_act(const bf16* __restrict__ H1,
                                             const float* __restrict__ p1s,
                                             const float* __restrict__ p1q,
                                             const float* __restrict__ g,
                                             const float* __restrict__ beta,
                                             bf16* __restrict__ A1) {
    __shared__ float s_sc[C2_], s_sh[C2_];
    for (int c = threadIdx.x; c < C2_; c += 256) {
        const float mean = p1s[c] * (1.0f / (float)M_);
        const float var  = p1q[c] * (1.0f / (float)M_) - mean * mean;
        const float inv  = rsqrtf(var + EPS_);
        const float scl  = g[c] * inv;
        s_sc[c] = scl;
        s_sh[c] = beta[c] - mean * scl;
    }
    __syncthreads();
    #pragma unroll
    for (int t = 0; t < 4; ++t) {
        const size_t chunk = (size_t)blockIdx.x * 1024 + t * 256 + threadIdx.x;
        const size_t i8 = chunk * 8;
        const int c0 = (int)(i8 % C2_);
        const bf16x8 v = *(const bf16x8*)&H1[i8];
        const float4 sca = *(const float4*)&s_sc[c0];
        const float4 scb = *(const float4*)&s_sc[c0 + 4];
        const float4 sha = *(const float4*)&s_sh[c0];
        const float4 shb = *(const float4*)&s_sh[c0 + 4];
        const float scs[8] = {sca.x, sca.y, sca.z, sca.w, scb.x, scb.y, scb.z, scb.w};
        const float shs[8] = {sha.x, sha.y, sha.z, sha.w, shb.x, shb.y, shb.z, shb.w};
        bf16x8 o;
        #pragma unroll
        for (int j = 0; j < 8; ++j)
            o[j] = (bf16)gelu_f(fmaf((float)v[j], scs[j], shs[j]));
        *(bf16x8*)&A1[i8] = o;
    }
}

// ---------------------------------------------------------------------------
// GEMM2: h2[m,o] = sum_c a1[m,c]*w2[o,c] + b2[o] -> bf16, fused stats
// 128x64 tile, BK=64, swizzled LDS, 4 waves x (4x2) frags
// grid (196, 3), block 256
__global__ __launch_bounds__(256) void k_gemm2(const bf16* __restrict__ A1,
                                               const bf16* __restrict__ W2,
                                               const float* __restrict__ bias,
                                               bf16* __restrict__ H2,
                                               float* __restrict__ psum,
                                               float* __restrict__ psq) {
    __shared__ bf16 As[128 * 64];
    __shared__ bf16 Bs[64 * 64];
    const int tid  = threadIdx.x;
    const int lane = tid & 63;
    const int wv   = tid >> 6;
    const int l16  = lane & 15;
    const int quad = lane >> 4;
    const int m0   = blockIdx.x * 128;
    const int n0   = blockIdx.y * 64;
    const int wm   = (wv & 1) * 64;
    const int wn   = (wv >> 1) * 32;

    f32x4 acc[4][2] = {};

    for (int kk = 0; kk < C2_; kk += 64) {
        __syncthreads();
        #pragma unroll
        for (int i = 0; i < 4; ++i) {
            const int qb = wv * 256 + i * 64;
            const int q  = qb + lane;
            const int r  = q >> 3;
            const int c8 = (q & 7) ^ (r & 7);
            gl_lds16(A1 + (size_t)(m0 + r) * C2_ + kk + c8 * 8, &As[qb * 8]);
        }
        #pragma unroll
        for (int i = 0; i < 2; ++i) {
            const int qb = wv * 128 + i * 64;
            const int q  = qb + lane;
            const int r  = q >> 3;
            const int c8 = (q & 7) ^ (r & 7);
            gl_lds16(W2 + (size_t)(n0 + r) * C2_ + kk + c8 * 8, &Bs[qb * 8]);
        }
        __syncthreads();
        #pragma unroll
        for (int ks = 0; ks < 2; ++ks) {
            bf16x8 af[4], bfr[2];
            #pragma unroll
            for (int f = 0; f < 4; ++f)
                af[f] = *(const bf16x8*)&As[sw_off(wm + f * 16 + l16, ks * 4 + quad)];
            #pragma unroll
            for (int f = 0; f < 2; ++f)
                bfr[f] = *(const bf16x8*)&Bs[sw_off(wn + f * 16 + l16, ks * 4 + quad)];
            #pragma unroll
            for (int mf = 0; mf < 4; ++mf)
                #pragma unroll
                for (int nf = 0; nf < 2; ++nf)
                    acc[mf][nf] = __builtin_amdgcn_mfma_f32_16x16x32_bf16(
                        af[mf], bfr[nf], acc[mf][nf], 0, 0, 0);
        }
    }

    #pragma unroll
    for (int nf = 0; nf < 2; ++nf) {
        const int col = n0 + wn + nf * 16 + l16;
        const float bv = bias[col];
        float s = 0.f, q = 0.f;
        #pragma unroll
        for (int mf = 0; mf < 4; ++mf) {
            #pragma unroll
            for (int r = 0; r < 4; ++r) {
                const float v = acc[mf][nf][r] + bv;
                s += v; q += v * v;
                H2[(size_t)(m0 + wm + mf * 16 + quad * 4 + r) * OUT_ + col] = (bf16)v;
            }
        }
        s += __shfl_xor(s, 16); s += __shfl_xor(s, 32);
        q += __shfl_xor(q, 16); q += __shfl_xor(q, 32);
        if (quad == 0) { atomicAdd(&psum[col], s); atomicAdd(&psq[col], q); }
    }
}

// ---------------------------------------------------------------------------
// Output: BN2+GELU + transpose [M,OUT] bf16 -> [B,OUT,N] fp32
// bf16x8 (16B) reads, BN2 params LDS-staged; float4 coalesced writes.
// grid (N/64, OUT/32, B), block 256
__global__ __launch_bounds__(256) void k_out(const bf16* __restrict__ H2,
                                             const float* __restrict__ p2s,
                                             const float* __restrict__ p2q,
                                             const float* __restrict__ g,
                                             const float* __restrict__ beta,
                                             float* __restrict__ out) {
    __shared__ float T[64][33];
    __shared__ float ssc[32], ssh[32];
    const int b  = blockIdx.z;
    const int o0 = blockIdx.y * 32;
    const int n0 = blockIdx.x * 64;
    const int tid = threadIdx.x;
    if (tid < 32) {
        const int o = o0 + tid;
        const float mean  = p2s[o] * (1.0f / (float)M_);
        const float var   = p2q[o] * (1.0f / (float)M_) - mean * mean;
        const float scale = g[o] * rsqrtf(var + EPS_);
        ssc[tid] = scale;
        ssh[tid] = beta[o] - mean * scale;
    }
    __syncthreads();
    {   // read: bf16x8 along o. oc = o-octet 0..3, n = 0..63
        const int oc = tid & 3;
        const int n  = tid >> 2;
        const bf16x8 h = *(const bf16x8*)&H2[((size_t)b * N_ + n0 + n) * OUT_ + o0 + 8 * oc];
        #pragma unroll
        for (int j = 0; j < 8; ++j) {
            const int ol = 8 * oc + j;
            T[n][ol] = gelu_f(fmaf((float)h[j], ssc[ol], ssh[ol]));
        }
    }
    __syncthreads();
    {   // write: float4 along n. u = n-quad 0..15, o = 0..15 then +16
        const int u  = tid & 15;
        const int ob = tid >> 4;          // 0..15
        #pragma unroll
        for (int p = 0; p < 2; ++p) {
            const int o = ob + p * 16;
            float4 v;
            v.x = T[4 * u + 0][o];
            v.y = T[4 * u + 1][o];
            v.z = T[4 * u + 2][o];
            v.w = T[4 * u + 3][o];
            *(float4*)&out[((size_t)b * OUT_ + o0 + o) * N_ + n0 + 4 * u] = v;
        }
    }
}

// ---------------------------------------------------------------------------
extern "C" void kernel_launch(void* const* d_in, const int* in_sizes, int n_in,
                              void* d_out, int out_size, void* d_ws, size_t ws_size,
                              hipStream_t stream) {
    const float* x     = (const float*)d_in[0];
    const int*   eidx  = (const int*)  d_in[1];
    const float* w1    = (const float*)d_in[2];
    const float* b1    = (const float*)d_in[3];
    const float* g1    = (const float*)d_in[4];
    const float* beta1 = (const float*)d_in[5];
    const float* w2    = (const float*)d_in[6];
    const float* b2    = (const float*)d_in[7];
    const float* g2    = (const float*)d_in[8];
    const float* beta2 = (const float*)d_in[9];
    float* out = (float*)d_out;

    char* ws = (char*)d_ws;
    size_t off = 0;
    bf16*  xt    = (bf16*)(ws + off); off += (size_t)M_ * C_  * sizeof(bf16);
    bf16*  dbuf  = (bf16*)(ws + off); off += (size_t)M_ * C_  * sizeof(bf16);
    bf16*  h1    = (bf16*)(ws + off); off += (size_t)M_ * C2_ * sizeof(bf16);
    bf16*  a1    = (bf16*)(ws + off); off += (size_t)M_ * C2_ * sizeof(bf16);
    bf16*  h2    = (bf16*)(ws + off); off += (size_t)M_ * OUT_ * sizeof(bf16);
    bf16*  w1p   = (bf16*)(ws + off); off += (size_t)C2_ * C2_ * sizeof(bf16);
    bf16*  w2b   = (bf16*)(ws + off); off += (size_t)OUT_ * C2_ * sizeof(bf16);
    float* stats = (float*)(ws + off); off += 1152 * sizeof(float);
    float* p1s = stats;        // 384
    float* p1q = stats + 384;  // 384
    float* p2s = stats + 768;  // 192
    float* p2q = stats + 960;  // 192

    k_pre<<<dim3(49, 3, 9), 256, 0, stream>>>(x, xt, w1, w2, w1p, w2b, stats);
    k_feats<<<M_ / 8, 192, 0, stream>>>(xt, eidx, dbuf);
    k_gemm1<<<dim3(M_ / 128, C2_ / 128), 256, 0, stream>>>(xt, dbuf, w1p, b1, h1, p1s, p1q);
    k_act<<<1176, 256, 0, stream>>>(h1, p1s, p1q, g1, beta1, a1);
    k_gemm2<<<dim3(M_ / 128, OUT_ / 64), 256, 0, stream>>>(a1, w2b, b2, h2, p2s, p2q);
    k_out<<<dim3(N_ / 64, OUT_ / 32, B_), 256, 0, stream>>>(h2, p2s, p2q, g2, beta2, out);
}